// Round 5
// baseline (2372.453 us; speedup 1.0000x reference)
//
#include <hip/hip_runtime.h>

typedef unsigned short u16;
typedef short s16x8 __attribute__((ext_vector_type(8)));
typedef float f32x4 __attribute__((ext_vector_type(4)));

#define LAYERS   64
#define M_NODES  2048
#define DIM      128
#define FD       512
#define CHUNK    16
#define NBLK     128     // M_NODES / CHUNK
#define TPB      512     // 8 waves; wave wv owns hidden dims [wv*16, wv*16+16)
#define XPAD     136     // 128 + 8 pad u16 (16B-aligned rows)
#define FLAGP    4       // flag padding: 16 B per flag (own cache slot)

__device__ __forceinline__ u16 f2bf(float f) {
    union { float f; unsigned int i; } v; v.f = f;
    unsigned int r = (v.i + 0x7FFFu + ((v.i >> 16) & 1u)) >> 16;
    return (u16)r;
}
__device__ __forceinline__ float sigm(float x) {
    return __builtin_amdgcn_rcpf(1.0f + __builtin_exp2f(-1.44269504f * x));
}
__device__ __forceinline__ float tanh_f(float x) {
    float ax = __builtin_fabsf(x);
    float t  = __builtin_exp2f(-2.88539008f * ax);   // exp(-2|x|)
    float r  = (1.0f - t) * __builtin_amdgcn_rcpf(1.0f + t);
    return __builtin_copysignf(r, x);
}

// ---------------- layer 0: emb[m] = basic_table[basic_names[m]]  (fp32 copy) ----------------
__global__ void l0_kernel(const int* __restrict__ names, const float* __restrict__ table,
                          float* __restrict__ emb) {
    int v = blockIdx.x * blockDim.x + threadIdx.x;      // 2048 rows * 32 float4
    if (v >= M_NODES * (DIM / 4)) return;
    int row = v >> 5, c = v & 31;
    const float4* src = (const float4*)(table + (size_t)names[row] * DIM);
    ((float4*)(emb + (size_t)row * DIM))[c] = src[c];
}

// ------------- repack W_m,U_m,W_s,U_s (fp32) into bf16 MFMA B-fragments in d_ws -------------
__global__ void repack_kernel(const float* __restrict__ Wm, const float* __restrict__ Um,
                              const float* __restrict__ Ws, const float* __restrict__ Us,
                              u16* __restrict__ packed, unsigned* __restrict__ flags) {
    int t = blockIdx.x * blockDim.x + threadIdx.x;      // 4*4*32*64 = 32768 threads
    if (t < NBLK * FLAGP) flags[t] = 0;                 // progress flags reset (per graph run)
    if (t >= 4 * 4 * 32 * 64) return;
    int lane = t & 63, ntg = (t >> 6) & 31, kc = (t >> 11) & 3, mat = t >> 13;
    const float* B = (mat == 0) ? Wm : (mat == 1) ? Um : (mat == 2) ? Ws : Us;
    int q = lane >> 4, nl = lane & 15;
    int kb = kc * 32 + q * 8;
    int n  = ntg * 16 + nl;
    u16* dst = packed + ((((size_t)mat * 4 + kc) * 32 + ntg) * 64 + lane) * 8;
    #pragma unroll
    for (int j = 0; j < 8; j++) dst[j] = f2bf(B[(size_t)(kb + j) * FD + n]);
}

// ======================= persistent fused kernel: all 63 layers, one launch =======================
// Coherence: emb stores are NORMAL cached writes. Per layer, after per-wave vmcnt drain +
// __syncthreads, tid0 publishes flags[b]=l with a RELEASE agent-scope atomic store — the compiler
// emits buffer_wbl2 sc1 (write back dirty L2 to L3, NO invalidate) before the flag store. Readers:
// rows are write-once and flag-gated before first read, so normal cached loads are safe and the
// data is served from L2/L3 (not HBM). Schedule: merged 5-step chain — LSTM_s t0 runs with
// LSTM_m t1 (both register-only), LSTM_s t1 with LSTM_m t3 (2x MFMA ILP); zxs precomputed in the
// parallel Zx phase. Next-layer gather rows are opportunistically prefetched into registers at
// step 3 (single flag check, no spin).
__global__ __launch_bounds__(TPB, 1) void fused_kernel(
    float* __restrict__ emb, const int* __restrict__ prop_ids, const int* __restrict__ super_ids,
    const float* __restrict__ Wm, const float* __restrict__ Um, const float* __restrict__ bm,
    const float* __restrict__ Ws, const float* __restrict__ Us, const float* __restrict__ bs,
    const float* __restrict__ empty, const u16* __restrict__ packed, unsigned* __restrict__ flags) {

    // slots 0..3: prop embeddings (slot 0 reused for h_m); slots 4..5: super embeddings
    __shared__ __align__(16) u16  xs[6][CHUNK][XPAD];   // bf16 A-operand tiles
    __shared__ __align__(16) u16  hbM[2][CHUNK][XPAD];  // LSTM_m h state, double-buffered
    __shared__ __align__(16) u16  hbS[2][CHUNK][XPAD];  // LSTM_s h state, double-buffered
    __shared__ float h1_s[DIM];

    const int tid  = threadIdx.x;
    const int b    = blockIdx.x;
    const int g0   = b * CHUNK;
    const int wv   = tid >> 6;          // 0..7
    const int lane = tid & 63;
    const int q    = lane >> 4, nl = lane & 15;
    const int d    = wv * 16 + nl;      // this lane's hidden dim

    auto ldB = [&](int mat, int kc, int g) -> s16x8 {
        return *(const s16x8*)(packed + ((((size_t)mat * 4 + kc) * 32 + (g * 8 + wv)) * 64 + lane) * 8);
    };
    auto load_afrag = [&](const u16* X /* [CHUNK][XPAD] base */, int kc) -> s16x8 {
        return *(const s16x8*)(X + (size_t)nl * XPAD + kc * 32 + q * 8);
    };

    float bzm[4], bzs[4];
    #pragma unroll
    for (int g = 0; g < 4; g++) { bzm[g] = bm[g * 128 + d]; bzs[g] = bs[g * 128 + d]; }

    // ---- layer-invariant LSTM_m t=0: x = empty, h = c = 0 (f32, once per kernel) ----
    float c1, h1;
    {
        float z0 = bzm[0], z1 = bzm[1], z2 = bzm[2], z3 = bzm[3];
        for (int k = 0; k < DIM; k++) {
            float e = empty[k];
            const float* Wr = Wm + (size_t)k * FD + d;
            z0 += e * Wr[0]; z1 += e * Wr[128]; z2 += e * Wr[256]; z3 += e * Wr[384];
        }
        (void)z1;                                   // f-gate irrelevant at c_prev = 0
        c1 = sigm(z0) * tanh_f(z2);                 // gate order i,f,g,o
        h1 = sigm(z3) * tanh_f(c1);
        if (q == 0) h1_s[d] = h1;                   // q==0 lanes cover all 128 dims
    }
    __syncthreads();

    // uh1[g] = (bf16(h1) @ U_m)[g*128+d]
    float uh1[4];
    {
        s16x8 ha[4];
        #pragma unroll
        for (int kc = 0; kc < 4; kc++)
            #pragma unroll
            for (int j = 0; j < 8; j++) ha[kc][j] = (short)f2bf(h1_s[kc * 32 + q * 8 + j]);
        f32x4 acc[4];
        #pragma unroll
        for (int g = 0; g < 4; g++) acc[g] = (f32x4){0.f, 0.f, 0.f, 0.f};
        #pragma unroll
        for (int kc = 0; kc < 4; kc++) {
            #pragma unroll
            for (int g = 0; g < 4; g++) {
                s16x8 u = ldB(1, kc, g);
                acc[g] = __builtin_amdgcn_mfma_f32_16x16x32_bf16(ha[kc], u, acc[g], 0, 0, 0);
            }
        }
        #pragma unroll
        for (int g = 0; g < 4; g++) uh1[g] = acc[g][0];  // all rows identical
    }

    // gates + store; mode 0: hbM[parity], 3: hbS[parity], 1: xs[0] (h_m), 2: emb (fp32 out)
    auto gates = [&](const f32x4* acc, const float* bz, float* cc, int mode, int parity, int l) {
        #pragma unroll
        for (int r2 = 0; r2 < 4; r2++) {
            int m = q * 4 + r2;
            float zi = acc[0][r2] + bz[0];
            float zf = acc[1][r2] + bz[1];
            float zg = acc[2][r2] + bz[2];
            float zo = acc[3][r2] + bz[3];
            float c  = sigm(zf) * cc[r2] + sigm(zi) * tanh_f(zg);
            cc[r2] = c;
            float h  = sigm(zo) * tanh_f(c);
            if (mode == 0)      hbM[parity][m][d] = f2bf(h);
            else if (mode == 3) hbS[parity][m][d] = f2bf(h);
            else if (mode == 1) xs[0][m][d] = f2bf(h);
            else emb[((size_t)l * M_NODES + g0 + m) * DIM + d] = h;
        }
    };

    // ---- gather-lane geometry (layer-invariant) + layer-1 index ----
    const bool isg = (tid < 384);
    int quarter = 0, slot = 0, node = 0, nidx = 0;
    if (isg) {
        quarter = tid & 3;
        int r = tid >> 2;
        slot = r >> 4;
        node = r & 15;
        if (slot < 4) nidx = prop_ids [((size_t)1 * M_NODES + g0 + node) * 4 + slot];
        else          nidx = super_ids[((size_t)1 * M_NODES + g0 + node) * 2 + (slot - 4)];
    }
    f32x4 vv[8];
    bool have = false;

    #pragma unroll 1
    for (int l = 1; l < LAYERS; l++) {
        const int gidx = nidx;
        // drain this block's layer-(l-1) emb stores into L2, sync, then RELEASE-publish
        asm volatile("s_waitcnt vmcnt(0)" ::: "memory");
        __syncthreads();                        // also protects xs/hb reuse across layers
        if (tid == 0)
            __hip_atomic_store(&flags[(size_t)b * FLAGP], (unsigned)l,
                               __ATOMIC_RELEASE, __HIP_MEMORY_SCOPE_AGENT);  // wbl2 + flag

        // ---- gather: prefetched rows skip the gate; rest are flag-gated ----
        if (isg) {
            if (!have) {
                const int gl = gidx >> 11;                  // row's layer
                const int wb = (gidx >> 4) & (NBLK - 1);    // row's writer block
                if (gl > 0 && wb != b) {
                    const unsigned* fp = flags + (size_t)wb * FLAGP;
                    while ((int)__hip_atomic_load(fp, __ATOMIC_RELAXED,
                                                  __HIP_MEMORY_SCOPE_AGENT) <= gl)
                        __builtin_amdgcn_s_sleep(1);
                }
                asm volatile("" ::: "memory");              // no load hoisting above the gate
                const f32x4* src = (const f32x4*)(emb + (size_t)gidx * DIM) + quarter * 8;
                #pragma unroll
                for (int j = 0; j < 8; j++) vv[j] = src[j];
            }
            // fp32 -> bf16 LDS tile (8B vector writes)
            u16* dst = &xs[slot][node][0];
            int e0 = quarter * 32;
            #pragma unroll
            for (int j = 0; j < 8; j++) {
                f32x4 v = vv[j];
                ushort4 w;
                w.x = f2bf(v[0]); w.y = f2bf(v[1]); w.z = f2bf(v[2]); w.w = f2bf(v[3]);
                *(ushort4*)(dst + e0 + j * 4) = w;
            }
        }
        have = false;
        __syncthreads();

        // ---- next-layer index (pure input) ----
        if (isg && (l + 1) < LAYERS) {
            if (slot < 4) nidx = prop_ids [((size_t)(l + 1) * M_NODES + g0 + node) * 4 + slot];
            else          nidx = super_ids[((size_t)(l + 1) * M_NODES + g0 + node) * 2 + (slot - 4)];
        }

        // ---- Zx: zxs0, zxs1 = sup@Ws (wfs dies after) ----
        f32x4 zxs0[4], zxs1[4];
        {
            s16x8 wfs[4][4];
            #pragma unroll
            for (int kc = 0; kc < 4; kc++)
                #pragma unroll
                for (int g = 0; g < 4; g++) wfs[kc][g] = ldB(2, kc, g);
            #pragma unroll
            for (int g = 0; g < 4; g++) { zxs0[g] = (f32x4){0.f,0.f,0.f,0.f}; zxs1[g] = (f32x4){0.f,0.f,0.f,0.f}; }
            #pragma unroll
            for (int kc = 0; kc < 4; kc++) {
                s16x8 a4 = load_afrag(&xs[4][0][0], kc);
                s16x8 a5 = load_afrag(&xs[5][0][0], kc);
                #pragma unroll
                for (int g = 0; g < 4; g++) {
                    zxs0[g] = __builtin_amdgcn_mfma_f32_16x16x32_bf16(a4, wfs[kc][g], zxs0[g], 0, 0, 0);
                    zxs1[g] = __builtin_amdgcn_mfma_f32_16x16x32_bf16(a5, wfs[kc][g], zxs1[g], 0, 0, 0);
                }
            }
        }
        // ---- Zx: zxm[0..3] = prop@Wm (wfm dies after) ----
        f32x4 zxm[4][4];
        {
            s16x8 wfm[4][4];
            #pragma unroll
            for (int kc = 0; kc < 4; kc++)
                #pragma unroll
                for (int g = 0; g < 4; g++) wfm[kc][g] = ldB(0, kc, g);
            #pragma unroll
            for (int s = 0; s < 4; s++) {
                #pragma unroll
                for (int g = 0; g < 4; g++) zxm[s][g] = (f32x4){0.f, 0.f, 0.f, 0.f};
                #pragma unroll
                for (int kc = 0; kc < 4; kc++) {
                    s16x8 a = load_afrag(&xs[s][0][0], kc);
                    #pragma unroll
                    for (int g = 0; g < 4; g++)
                        zxm[s][g] = __builtin_amdgcn_mfma_f32_16x16x32_bf16(a, wfm[kc][g], zxm[s][g], 0, 0, 0);
                }
            }
        }

        s16x8 ufm[4][4];
        #pragma unroll
        for (int kc = 0; kc < 4; kc++)
            #pragma unroll
            for (int g = 0; g < 4; g++) ufm[kc][g] = ldB(1, kc, g);

        float ccm[4] = {c1, c1, c1, c1};
        float ccs[4] = {0.f, 0.f, 0.f, 0.f};

        {   // step1: m-t1 (zxm[0]+uh1) + s-t0 (zxs0) — register-only
            f32x4 accM[4];
            #pragma unroll
            for (int g = 0; g < 4; g++) accM[g] = zxm[0][g] + uh1[g];
            gates(accM, bzm, ccm, 0, 1, l);            // write hbM[1]
            gates(zxs0, bzs, ccs, 3, 0, l);            // write hbS[0]
        }
        __syncthreads();                               // A

        {   // step2: m-t2 = zxm[1] + hbM[1]@Um
            f32x4 acc[4];
            #pragma unroll
            for (int g = 0; g < 4; g++) acc[g] = zxm[1][g];
            #pragma unroll
            for (int kc = 0; kc < 4; kc++) {
                s16x8 a = load_afrag(&hbM[1][0][0], kc);
                #pragma unroll
                for (int g = 0; g < 4; g++)
                    acc[g] = __builtin_amdgcn_mfma_f32_16x16x32_bf16(a, ufm[kc][g], acc[g], 0, 0, 0);
            }
            gates(acc, bzm, ccm, 0, 0, l);             // write hbM[0]
        }
        __syncthreads();                               // B

        s16x8 ufs[4][4];
        #pragma unroll
        for (int kc = 0; kc < 4; kc++)
            #pragma unroll
            for (int g = 0; g < 4; g++) ufs[kc][g] = ldB(3, kc, g);

        {   // step3: m-t3 (zxm[2] + hbM[0]@Um)  ||  s-t1 (zxs1 + hbS[0]@Us) — 2x ILP
            f32x4 am[4], as_[4];
            #pragma unroll
            for (int g = 0; g < 4; g++) { am[g] = zxm[2][g]; as_[g] = zxs1[g]; }
            #pragma unroll
            for (int kc = 0; kc < 4; kc++) {
                s16x8 aM = load_afrag(&hbM[0][0][0], kc);
                s16x8 aS = load_afrag(&hbS[0][0][0], kc);
                #pragma unroll
                for (int g = 0; g < 4; g++) {
                    am[g]  = __builtin_amdgcn_mfma_f32_16x16x32_bf16(aM, ufm[kc][g], am[g],  0, 0, 0);
                    as_[g] = __builtin_amdgcn_mfma_f32_16x16x32_bf16(aS, ufs[kc][g], as_[g], 0, 0, 0);
                }
            }
            gates(am,  bzm, ccm, 0, 1, l);             // write hbM[1]
            gates(as_, bzs, ccs, 3, 1, l);             // write hbS[1]
        }
        // ---- opportunistic next-layer row prefetch (single flag check, no spin) ----
        if (isg && (l + 1) < LAYERS) {
            const int gl = nidx >> 11;
            const int wbn = (nidx >> 4) & (NBLK - 1);
            bool rdy = (gl == 0) || (wbn == b && gl < l) ||
                       (wbn != b && (int)__hip_atomic_load(flags + (size_t)wbn * FLAGP,
                            __ATOMIC_RELAXED, __HIP_MEMORY_SCOPE_AGENT) > gl);
            if (rdy) {
                asm volatile("" ::: "memory");
                const f32x4* srcp = (const f32x4*)(emb + (size_t)nidx * DIM) + quarter * 8;
                #pragma unroll
                for (int j = 0; j < 8; j++) vv[j] = srcp[j];
                have = true;
            }
        }
        __syncthreads();                               // C

        {   // step4: m-t4 = zxm[3] + hbM[1]@Um -> h_m into xs[0]
            f32x4 acc[4];
            #pragma unroll
            for (int g = 0; g < 4; g++) acc[g] = zxm[3][g];
            #pragma unroll
            for (int kc = 0; kc < 4; kc++) {
                s16x8 a = load_afrag(&hbM[1][0][0], kc);
                #pragma unroll
                for (int g = 0; g < 4; g++)
                    acc[g] = __builtin_amdgcn_mfma_f32_16x16x32_bf16(a, ufm[kc][g], acc[g], 0, 0, 0);
            }
            gates(acc, bzm, ccm, 1, 0, l);             // h_m -> xs[0]
        }
        __syncthreads();                               // D

        {   // step5: s-t2 = h_m@Ws + hbS[1]@Us -> fp32 layer output (normal cached store)
            s16x8 wfs2[4][4];
            #pragma unroll
            for (int kc = 0; kc < 4; kc++)
                #pragma unroll
                for (int g = 0; g < 4; g++) wfs2[kc][g] = ldB(2, kc, g);
            f32x4 acc[4];
            #pragma unroll
            for (int g = 0; g < 4; g++) acc[g] = (f32x4){0.f, 0.f, 0.f, 0.f};
            #pragma unroll
            for (int kc = 0; kc < 4; kc++) {
                s16x8 a0 = load_afrag(&xs[0][0][0], kc);
                s16x8 aS = load_afrag(&hbS[1][0][0], kc);
                #pragma unroll
                for (int g = 0; g < 4; g++) {
                    acc[g] = __builtin_amdgcn_mfma_f32_16x16x32_bf16(a0, wfs2[kc][g], acc[g], 0, 0, 0);
                    acc[g] = __builtin_amdgcn_mfma_f32_16x16x32_bf16(aS, ufs[kc][g],  acc[g], 0, 0, 0);
                }
            }
            gates(acc, bzs, ccs, 2, 0, l);             // emb out
        }
    }
}

// ----------------------------- fallback: proven per-layer kernel -----------------------------
template <bool PACKED>
__global__ __launch_bounds__(TPB, 1) void layer_kernel(
    float* __restrict__ emb, const int* __restrict__ prop_ids, const int* __restrict__ super_ids,
    const float* __restrict__ Wm, const float* __restrict__ Um, const float* __restrict__ bm,
    const float* __restrict__ Ws, const float* __restrict__ Us, const float* __restrict__ bs,
    const float* __restrict__ empty, const u16* __restrict__ packed, int l) {

    __shared__ __align__(16) u16  xs[6][CHUNK][XPAD];
    __shared__ __align__(16) u16  hbuf[2][CHUNK][XPAD];
    __shared__ __align__(16) u16  empty_s[XPAD];

    const int tid  = threadIdx.x;
    const int b    = blockIdx.x;
    const int g0   = b * CHUNK;
    const size_t row0 = (size_t)l * M_NODES + g0;

    const int wv   = tid >> 6;
    const int lane = tid & 63;
    const int q    = lane >> 4, nl = lane & 15;
    const int d    = wv * 16 + nl;

    if (tid < 384) {
        int quarter = tid & 3;
        int r    = tid >> 2;
        int slot = r >> 4;
        int node = r & 15;
        size_t idx;
        if (slot < 4) idx = (size_t)prop_ids [((size_t)l * M_NODES + g0 + node) * 4 + slot];
        else          idx = (size_t)super_ids[((size_t)l * M_NODES + g0 + node) * 2 + (slot - 4)];
        const float4* src = (const float4*)(emb + idx * DIM);
        u16* dst = &xs[slot][node][0];
        int e0 = quarter * 32;
        #pragma unroll
        for (int j = 0; j < 8; j++) {
            float4 v = src[(e0 >> 2) + j];
            int o = e0 + j * 4;
            dst[o] = f2bf(v.x); dst[o + 1] = f2bf(v.y);
            dst[o + 2] = f2bf(v.z); dst[o + 3] = f2bf(v.w);
        }
    } else if (tid < 384 + 128) {
        int dd = tid - 384;
        empty_s[dd] = f2bf(empty[dd]);
    }
    __syncthreads();

    auto load_bfrag_packed = [&](int mat, int kc, int g) -> s16x8 {
        return *(const s16x8*)(packed + ((((size_t)mat * 4 + kc) * 32 + (g * 8 + wv)) * 64 + lane) * 8);
    };
    auto load_bfrag_direct = [&](const float* B, int kc, int g) -> s16x8 {
        int kb = kc * 32 + q * 8;
        int n  = g * 128 + d;
        s16x8 f;
        #pragma unroll
        for (int j = 0; j < 8; j++) f[j] = (short)f2bf(B[(size_t)(kb + j) * FD + n]);
        return f;
    };
    auto load_afrag = [&](const u16* X, int kc) -> s16x8 {
        return *(const s16x8*)(X + (size_t)nl * XPAD + kc * 32 + q * 8);
    };

    auto run_phase = [&](const float* Wg, const float* Ug, const float* bias,
                         int matW, int matU, int nsteps, const int* slots,
                         bool write_hm, bool write_out) {
        s16x8 wf[4][4], uf[4][4];
        #pragma unroll
        for (int kc = 0; kc < 4; kc++) {
            #pragma unroll
            for (int g = 0; g < 4; g++) {
                if (PACKED) { wf[kc][g] = load_bfrag_packed(matW, kc, g);
                              uf[kc][g] = load_bfrag_packed(matU, kc, g); }
                else        { wf[kc][g] = load_bfrag_direct(Wg, kc, g);
                              uf[kc][g] = load_bfrag_direct(Ug, kc, g); }
            }
        }
        float bz[4];
        #pragma unroll
        for (int g = 0; g < 4; g++) bz[g] = bias[g * 128 + d];
        float cc[4] = {0.f, 0.f, 0.f, 0.f};

        #pragma unroll 1
        for (int t = 0; t < nsteps; t++) {
            int s = slots[t];
            f32x4 acc[4];
            #pragma unroll
            for (int g = 0; g < 4; g++) acc[g] = (f32x4){0.f, 0.f, 0.f, 0.f};
            #pragma unroll
            for (int kc = 0; kc < 4; kc++) {
                s16x8 a = (s < 0) ? *(const s16x8*)(&empty_s[kc * 32 + q * 8])
                                  : load_afrag(&xs[s][0][0], kc);
                #pragma unroll
                for (int g = 0; g < 4; g++)
                    acc[g] = __builtin_amdgcn_mfma_f32_16x16x32_bf16(a, wf[kc][g], acc[g], 0, 0, 0);
            }
            if (t > 0) {
                __syncthreads();
                const u16* hb = &hbuf[(t - 1) & 1][0][0];
                #pragma unroll
                for (int kc = 0; kc < 4; kc++) {
                    s16x8 a = load_afrag(hb, kc);
                    #pragma unroll
                    for (int g = 0; g < 4; g++)
                        acc[g] = __builtin_amdgcn_mfma_f32_16x16x32_bf16(a, uf[kc][g], acc[g], 0, 0, 0);
                }
            }
            bool last = (t == nsteps - 1);
            #pragma unroll
            for (int r2 = 0; r2 < 4; r2++) {
                int m = q * 4 + r2;
                float zi = acc[0][r2] + bz[0];
                float zf = acc[1][r2] + bz[1];
                float zg = acc[2][r2] + bz[2];
                float zo = acc[3][r2] + bz[3];
                float c  = sigm(zf) * cc[r2] + sigm(zi) * tanh_f(zg);
                cc[r2] = c;
                float h  = sigm(zo) * tanh_f(c);
                if (!last)          hbuf[t & 1][m][d] = f2bf(h);
                else if (write_hm)  xs[0][m][d] = f2bf(h);
                else if (write_out) emb[(row0 + m) * DIM + d] = h;
            }
        }
    };

    {
        const int slots_m[5] = {-1, 0, 1, 2, 3};
        run_phase(Wm, Um, bm, 0, 1, 5, slots_m, true, false);
    }
    {
        const int slots_s[3] = {4, 5, 0};
        run_phase(Ws, Us, bs, 2, 3, 3, slots_s, false, true);
    }
}

extern "C" void kernel_launch(void* const* d_in, const int* in_sizes, int n_in,
                              void* d_out, int out_size, void* d_ws, size_t ws_size,
                              hipStream_t stream) {
    const int*   names = (const int*)d_in[0];
    const int*   pids  = (const int*)d_in[1];
    const int*   sids  = (const int*)d_in[2];
    const float* table = (const float*)d_in[3];
    const float* Wm    = (const float*)d_in[4];
    const float* Um    = (const float*)d_in[5];
    const float* bm    = (const float*)d_in[6];
    const float* Ws    = (const float*)d_in[7];
    const float* Us    = (const float*)d_in[8];
    const float* bs    = (const float*)d_in[9];
    const float* empt  = (const float*)d_in[10];
    float* emb  = (float*)d_out;
    u16* packed = (u16*)d_ws;

    l0_kernel<<<256, 256, 0, stream>>>(names, table, emb);

    const size_t packed_bytes = (size_t)4 * 4 * 32 * 64 * 8 * sizeof(u16);  // 512 KB
    const bool ws_ok = ws_size >= packed_bytes + NBLK * FLAGP * sizeof(unsigned);

    if (ws_ok) {
        unsigned* flags = (unsigned*)((char*)d_ws + packed_bytes);
        repack_kernel<<<128, 256, 0, stream>>>(Wm, Um, Ws, Us, packed, flags);

        void* args[] = {(void*)&emb, (void*)&pids, (void*)&sids, (void*)&Wm, (void*)&Um, (void*)&bm,
                        (void*)&Ws, (void*)&Us, (void*)&bs, (void*)&empt, (void*)&packed, (void*)&flags};
        void (*kptr)(float*, const int*, const int*, const float*, const float*, const float*,
                     const float*, const float*, const float*, const float*, const u16*, unsigned*) =
            fused_kernel;
        hipError_t err = hipLaunchCooperativeKernel((const void*)kptr, dim3(NBLK), dim3(TPB),
                                                    args, 0, stream);
        if (err == hipSuccess) return;
        // coop launch failed -> proven per-layer path (packed)
        for (int l = 1; l < LAYERS; l++)
            layer_kernel<true><<<NBLK, TPB, 0, stream>>>(emb, pids, sids, Wm, Um, bm,
                                                         Ws, Us, bs, empt, packed, l);
    } else {
        for (int l = 1; l < LAYERS; l++)
            layer_kernel<false><<<NBLK, TPB, 0, stream>>>(emb, pids, sids, Wm, Um, bm,
                                                          Ws, Us, bs, empt, packed, l);
    }
}

// Round 6
// 1088.616 us; speedup vs baseline: 2.1793x; 2.1793x over previous
//
#include <hip/hip_runtime.h>

typedef unsigned short u16;
typedef short s16x8 __attribute__((ext_vector_type(8)));
typedef float f32x4 __attribute__((ext_vector_type(4)));

#define LAYERS   64
#define M_NODES  2048
#define DIM      128
#define FD       512
#define CHUNK    16
#define NBLK     128     // M_NODES / CHUNK
#define TPB      512     // 8 waves; wave wv owns hidden dims [wv*16, wv*16+16)
#define XPAD     136     // 128 + 8 pad u16 (16B-aligned rows)

__device__ __forceinline__ u16 f2bf(float f) {
    union { float f; unsigned int i; } v; v.f = f;
    unsigned int r = (v.i + 0x7FFFu + ((v.i >> 16) & 1u)) >> 16;
    return (u16)r;
}
__device__ __forceinline__ float bf2f(u16 h) {
    union { unsigned int i; float f; } v; v.i = ((unsigned int)h) << 16;
    return v.f;
}
__device__ __forceinline__ float sigm(float x) {
    return __builtin_amdgcn_rcpf(1.0f + __builtin_exp2f(-1.44269504f * x));
}
__device__ __forceinline__ float tanh_f(float x) {
    float ax = __builtin_fabsf(x);
    float t  = __builtin_exp2f(-2.88539008f * ax);   // exp(-2|x|)
    float r  = (1.0f - t) * __builtin_amdgcn_rcpf(1.0f + t);
    return __builtin_copysignf(r, x);
}

// ---------------- layer 0: emb[m] = basic_table[basic_names[m]]  (fp32 copy) ----------------
__global__ void l0_kernel(const int* __restrict__ names, const float* __restrict__ table,
                          float* __restrict__ emb) {
    int v = blockIdx.x * blockDim.x + threadIdx.x;      // 2048 rows * 32 float4
    if (v >= M_NODES * (DIM / 4)) return;
    int row = v >> 5, c = v & 31;
    const float4* src = (const float4*)(table + (size_t)names[row] * DIM);
    ((float4*)(emb + (size_t)row * DIM))[c] = src[c];
}

// ------------- repack W_m,U_m,W_s,U_s (fp32) into bf16 MFMA B-fragments in d_ws -------------
__global__ void repack_kernel(const float* __restrict__ Wm, const float* __restrict__ Um,
                              const float* __restrict__ Ws, const float* __restrict__ Us,
                              u16* __restrict__ packed) {
    int t = blockIdx.x * blockDim.x + threadIdx.x;      // 4*4*32*64 = 32768 threads
    if (t >= 4 * 4 * 32 * 64) return;
    int lane = t & 63, ntg = (t >> 6) & 31, kc = (t >> 11) & 3, mat = t >> 13;
    const float* B = (mat == 0) ? Wm : (mat == 1) ? Um : (mat == 2) ? Ws : Us;
    int q = lane >> 4, nl = lane & 15;
    int kb = kc * 32 + q * 8;
    int n  = ntg * 16 + nl;
    u16* dst = packed + ((((size_t)mat * 4 + kc) * 32 + ntg) * 64 + lane) * 8;
    #pragma unroll
    for (int j = 0; j < 8; j++) dst[j] = f2bf(B[(size_t)(kb + j) * FD + n]);
}

// ------------- one-time t=0 hoist: c1[d], uh1[g][d] for the layer-invariant LSTM_m t=0 -------------
// t0buf layout: [0..127] = c1; [128 + g*128 + d] = uh1[g][d]
__global__ void init_t0_kernel(const float* __restrict__ Wm, const float* __restrict__ Um,
                               const float* __restrict__ bm, const float* __restrict__ empty,
                               float* __restrict__ t0buf) {
    __shared__ float h1s[DIM];
    int dd = threadIdx.x;                              // 128 threads
    if (dd < DIM) {
        float z0 = bm[dd], z1 = bm[256 + dd], z2 = bm[384 + dd];
        for (int k = 0; k < DIM; k++) {
            float e = empty[k];
            const float* Wr = Wm + (size_t)k * FD;
            z0 += e * Wr[dd];                          // i gate
            z1 += e * Wr[256 + dd];                    // g gate
            z2 += e * Wr[384 + dd];                    // o gate  (f gate irrelevant: c_prev=0)
        }
        float c1 = sigm(z0) * tanh_f(z1);
        float h1 = sigm(z2) * tanh_f(c1);
        t0buf[dd] = c1;
        h1s[dd] = h1;
    }
    __syncthreads();
    if (dd < DIM) {
        float u0 = 0.f, u1 = 0.f, u2 = 0.f, u3 = 0.f;
        for (int k = 0; k < DIM; k++) {
            float hb = bf2f(f2bf(h1s[k]));             // same bf16 rounding as the MFMA path
            const float* Ur = Um + (size_t)k * FD;
            u0 += hb * bf2f(f2bf(Ur[dd]));
            u1 += hb * bf2f(f2bf(Ur[128 + dd]));
            u2 += hb * bf2f(f2bf(Ur[256 + dd]));
            u3 += hb * bf2f(f2bf(Ur[384 + dd]));
        }
        t0buf[128 + 0 * 128 + dd] = u0;
        t0buf[128 + 1 * 128 + dd] = u1;
        t0buf[128 + 2 * 128 + dd] = u2;
        t0buf[128 + 3 * 128 + dd] = u3;
    }
}

// ======================= per-layer kernel, merged 5-step schedule =======================
// Coherence via dispatch boundaries (proven cheapest across r1-r5 experiments). Per layer:
// gather -> Zx precompute (all x@W: zxs0, zxs1, zxm[0..3]) -> 5 barrier-steps:
//   step1 (reg-only): m-t1 = zxm0+uh1 (cc=c1)  ||  s-t0 = zxs0
//   step2: m-t2 = zxm1 + hbM@Um
//   step3: m-t3 = zxm2 + hbM@Um  ||  s-t1 = zxs1 + hbS@Us   (2x MFMA ILP)
//   step4: m-t4 = zxm3 + hbM@Um -> h_m -> xs[0]
//   step5: s-t2 = h_m@Ws + hbS@Us -> emb
// vs baseline: 8 -> 5 barrier-steps, 224 -> 192 MFMAs, t0 step removed (precomputed).
__global__ __launch_bounds__(TPB, 1) void layer5_kernel(
    float* __restrict__ emb, const int* __restrict__ prop_ids, const int* __restrict__ super_ids,
    const float* __restrict__ bm, const float* __restrict__ bs,
    const u16* __restrict__ packed, const float* __restrict__ t0buf, int l) {

    // slots 0..3: prop embeddings (slot 0 reused for h_m); slots 4..5: super embeddings
    __shared__ __align__(16) u16 xs[6][CHUNK][XPAD];
    __shared__ __align__(16) u16 hbM[2][CHUNK][XPAD];
    __shared__ __align__(16) u16 hbS[2][CHUNK][XPAD];

    const int tid  = threadIdx.x;
    const int b    = blockIdx.x;
    const int g0   = b * CHUNK;
    const int wv   = tid >> 6;          // 0..7
    const int lane = tid & 63;
    const int q    = lane >> 4, nl = lane & 15;
    const int d    = wv * 16 + nl;      // this lane's hidden dim

    auto ldB = [&](int mat, int kc, int g) -> s16x8 {
        return *(const s16x8*)(packed + ((((size_t)mat * 4 + kc) * 32 + (g * 8 + wv)) * 64 + lane) * 8);
    };
    auto load_afrag = [&](const u16* X /* [CHUNK][XPAD] base */, int kc) -> s16x8 {
        return *(const s16x8*)(X + (size_t)nl * XPAD + kc * 32 + q * 8);
    };

    // ---- gather: 96 fp32 rows -> bf16 LDS tiles (waves 0-5) ----
    if (tid < 384) {
        int quarter = tid & 3;
        int r    = tid >> 2;
        int slot = r >> 4;
        int node = r & 15;
        size_t idx;
        if (slot < 4) idx = (size_t)prop_ids [((size_t)l * M_NODES + g0 + node) * 4 + slot];
        else          idx = (size_t)super_ids[((size_t)l * M_NODES + g0 + node) * 2 + (slot - 4)];
        const f32x4* src = (const f32x4*)(emb + idx * DIM) + quarter * 8;
        u16* dst = &xs[slot][node][0];
        int e0 = quarter * 32;
        #pragma unroll
        for (int j = 0; j < 8; j++) {
            f32x4 v = src[j];
            ushort4 w;
            w.x = f2bf(v[0]); w.y = f2bf(v[1]); w.z = f2bf(v[2]); w.w = f2bf(v[3]);
            *(ushort4*)(dst + e0 + j * 4) = w;
        }
    }

    // ---- per-thread constants (all waves, overlaps gather) ----
    float bzm[4], bzs[4], uh1[4];
    #pragma unroll
    for (int g = 0; g < 4; g++) {
        bzm[g] = bm[g * 128 + d];
        bzs[g] = bs[g * 128 + d];
        uh1[g] = t0buf[128 + g * 128 + d];
    }
    const float c1 = t0buf[d];

    // Ws fragments for the Zx phase (dies after zxs; reloaded at step5)
    s16x8 wfs[4][4];
    #pragma unroll
    for (int kc = 0; kc < 4; kc++)
        #pragma unroll
        for (int g = 0; g < 4; g++) wfs[kc][g] = ldB(2, kc, g);

    __syncthreads();                                   // S0: gather visible

    // gates + store; mode 0: hbM[parity], 3: hbS[parity], 1: xs[0] (h_m), 2: emb (fp32 out)
    auto gates = [&](const f32x4* acc, const float* bz, float* cc, int mode, int parity) {
        #pragma unroll
        for (int r2 = 0; r2 < 4; r2++) {
            int m = q * 4 + r2;
            float zi = acc[0][r2] + bz[0];
            float zf = acc[1][r2] + bz[1];
            float zg = acc[2][r2] + bz[2];
            float zo = acc[3][r2] + bz[3];
            float c  = sigm(zf) * cc[r2] + sigm(zi) * tanh_f(zg);
            cc[r2] = c;
            float h  = sigm(zo) * tanh_f(c);
            if (mode == 0)      hbM[parity][m][d] = f2bf(h);
            else if (mode == 3) hbS[parity][m][d] = f2bf(h);
            else if (mode == 1) xs[0][m][d] = f2bf(h);
            else emb[((size_t)l * M_NODES + g0 + m) * DIM + d] = h;
        }
    };

    // ---- Zx: zxs0, zxs1 = sup@Ws ----
    f32x4 zxs0[4], zxs1[4];
    #pragma unroll
    for (int g = 0; g < 4; g++) { zxs0[g] = (f32x4){0.f,0.f,0.f,0.f}; zxs1[g] = (f32x4){0.f,0.f,0.f,0.f}; }
    #pragma unroll
    for (int kc = 0; kc < 4; kc++) {
        s16x8 a4 = load_afrag(&xs[4][0][0], kc);
        s16x8 a5 = load_afrag(&xs[5][0][0], kc);
        #pragma unroll
        for (int g = 0; g < 4; g++) {
            zxs0[g] = __builtin_amdgcn_mfma_f32_16x16x32_bf16(a4, wfs[kc][g], zxs0[g], 0, 0, 0);
            zxs1[g] = __builtin_amdgcn_mfma_f32_16x16x32_bf16(a5, wfs[kc][g], zxs1[g], 0, 0, 0);
        }
    }
    // ---- Zx: zxm[0..3] = prop@Wm (wfm scoped to die after) ----
    f32x4 zxm[4][4];
    {
        s16x8 wfm[4][4];
        #pragma unroll
        for (int kc = 0; kc < 4; kc++)
            #pragma unroll
            for (int g = 0; g < 4; g++) wfm[kc][g] = ldB(0, kc, g);
        #pragma unroll
        for (int s = 0; s < 4; s++) {
            #pragma unroll
            for (int g = 0; g < 4; g++) zxm[s][g] = (f32x4){0.f, 0.f, 0.f, 0.f};
            #pragma unroll
            for (int kc = 0; kc < 4; kc++) {
                s16x8 a = load_afrag(&xs[s][0][0], kc);
                #pragma unroll
                for (int g = 0; g < 4; g++)
                    zxm[s][g] = __builtin_amdgcn_mfma_f32_16x16x32_bf16(a, wfm[kc][g], zxm[s][g], 0, 0, 0);
            }
        }
    }

    s16x8 ufm[4][4];
    #pragma unroll
    for (int kc = 0; kc < 4; kc++)
        #pragma unroll
        for (int g = 0; g < 4; g++) ufm[kc][g] = ldB(1, kc, g);

    float ccm[4] = {c1, c1, c1, c1};
    float ccs[4] = {0.f, 0.f, 0.f, 0.f};

    {   // step1 (register-only): m-t1 = zxm[0]+uh1  ||  s-t0 = zxs0
        f32x4 accM[4];
        #pragma unroll
        for (int g = 0; g < 4; g++) accM[g] = zxm[0][g] + uh1[g];
        gates(accM, bzm, ccm, 0, 1);                   // write hbM[1]
        gates(zxs0, bzs, ccs, 3, 0);                   // write hbS[0]
    }
    __syncthreads();                                   // S1

    {   // step2: m-t2 = zxm[1] + hbM[1]@Um
        f32x4 acc[4];
        #pragma unroll
        for (int g = 0; g < 4; g++) acc[g] = zxm[1][g];
        #pragma unroll
        for (int kc = 0; kc < 4; kc++) {
            s16x8 a = load_afrag(&hbM[1][0][0], kc);
            #pragma unroll
            for (int g = 0; g < 4; g++)
                acc[g] = __builtin_amdgcn_mfma_f32_16x16x32_bf16(a, ufm[kc][g], acc[g], 0, 0, 0);
        }
        gates(acc, bzm, ccm, 0, 0);                    // write hbM[0]
    }
    __syncthreads();                                   // S2

    s16x8 ufs[4][4];
    #pragma unroll
    for (int kc = 0; kc < 4; kc++)
        #pragma unroll
        for (int g = 0; g < 4; g++) ufs[kc][g] = ldB(3, kc, g);

    {   // step3: m-t3 (zxm[2] + hbM[0]@Um)  ||  s-t1 (zxs1 + hbS[0]@Us) — 2x MFMA ILP
        f32x4 am[4], as_[4];
        #pragma unroll
        for (int g = 0; g < 4; g++) { am[g] = zxm[2][g]; as_[g] = zxs1[g]; }
        #pragma unroll
        for (int kc = 0; kc < 4; kc++) {
            s16x8 aM = load_afrag(&hbM[0][0][0], kc);
            s16x8 aS = load_afrag(&hbS[0][0][0], kc);
            #pragma unroll
            for (int g = 0; g < 4; g++) {
                am[g]  = __builtin_amdgcn_mfma_f32_16x16x32_bf16(aM, ufm[kc][g], am[g],  0, 0, 0);
                as_[g] = __builtin_amdgcn_mfma_f32_16x16x32_bf16(aS, ufs[kc][g], as_[g], 0, 0, 0);
            }
        }
        gates(am,  bzm, ccm, 0, 1);                    // write hbM[1]
        gates(as_, bzs, ccs, 3, 1);                    // write hbS[1]
    }
    __syncthreads();                                   // S3

    {   // step4: m-t4 = zxm[3] + hbM[1]@Um -> h_m -> xs[0]
        f32x4 acc[4];
        #pragma unroll
        for (int g = 0; g < 4; g++) acc[g] = zxm[3][g];
        #pragma unroll
        for (int kc = 0; kc < 4; kc++) {
            s16x8 a = load_afrag(&hbM[1][0][0], kc);
            #pragma unroll
            for (int g = 0; g < 4; g++)
                acc[g] = __builtin_amdgcn_mfma_f32_16x16x32_bf16(a, ufm[kc][g], acc[g], 0, 0, 0);
        }
        gates(acc, bzm, ccm, 1, 0);                    // h_m -> xs[0]
    }
    __syncthreads();                                   // S4

    {   // step5: s-t2 = h_m@Ws + hbS[1]@Us -> fp32 layer output
        s16x8 wfs2[4][4];
        #pragma unroll
        for (int kc = 0; kc < 4; kc++)
            #pragma unroll
            for (int g = 0; g < 4; g++) wfs2[kc][g] = ldB(2, kc, g);
        f32x4 acc[4];
        #pragma unroll
        for (int g = 0; g < 4; g++) acc[g] = (f32x4){0.f, 0.f, 0.f, 0.f};
        #pragma unroll
        for (int kc = 0; kc < 4; kc++) {
            s16x8 a0 = load_afrag(&xs[0][0][0], kc);
            s16x8 aS = load_afrag(&hbS[1][0][0], kc);
            #pragma unroll
            for (int g = 0; g < 4; g++) {
                acc[g] = __builtin_amdgcn_mfma_f32_16x16x32_bf16(a0, wfs2[kc][g], acc[g], 0, 0, 0);
                acc[g] = __builtin_amdgcn_mfma_f32_16x16x32_bf16(aS, ufs[kc][g],  acc[g], 0, 0, 0);
            }
        }
        gates(acc, bzs, ccs, 2, 0);                    // emb out
    }
}

// ----------------------------- fallback (no workspace): proven per-layer kernel -----------------------------
__global__ __launch_bounds__(TPB, 1) void layer_kernel_direct(
    float* __restrict__ emb, const int* __restrict__ prop_ids, const int* __restrict__ super_ids,
    const float* __restrict__ Wm, const float* __restrict__ Um, const float* __restrict__ bm,
    const float* __restrict__ Ws, const float* __restrict__ Us, const float* __restrict__ bs,
    const float* __restrict__ empty, int l) {

    __shared__ __align__(16) u16  xs[6][CHUNK][XPAD];
    __shared__ __align__(16) u16  hbuf[2][CHUNK][XPAD];
    __shared__ __align__(16) u16  empty_s[XPAD];

    const int tid  = threadIdx.x;
    const int b    = blockIdx.x;
    const int g0   = b * CHUNK;
    const size_t row0 = (size_t)l * M_NODES + g0;

    const int wv   = tid >> 6;
    const int lane = tid & 63;
    const int q    = lane >> 4, nl = lane & 15;
    const int d    = wv * 16 + nl;

    if (tid < 384) {
        int quarter = tid & 3;
        int r    = tid >> 2;
        int slot = r >> 4;
        int node = r & 15;
        size_t idx;
        if (slot < 4) idx = (size_t)prop_ids [((size_t)l * M_NODES + g0 + node) * 4 + slot];
        else          idx = (size_t)super_ids[((size_t)l * M_NODES + g0 + node) * 2 + (slot - 4)];
        const float4* src = (const float4*)(emb + idx * DIM);
        u16* dst = &xs[slot][node][0];
        int e0 = quarter * 32;
        #pragma unroll
        for (int j = 0; j < 8; j++) {
            float4 v = src[(e0 >> 2) + j];
            int o = e0 + j * 4;
            dst[o] = f2bf(v.x); dst[o + 1] = f2bf(v.y);
            dst[o + 2] = f2bf(v.z); dst[o + 3] = f2bf(v.w);
        }
    } else if (tid < 384 + 128) {
        int dd = tid - 384;
        empty_s[dd] = f2bf(empty[dd]);
    }
    __syncthreads();

    auto load_bfrag_direct = [&](const float* B, int kc, int g) -> s16x8 {
        int kb = kc * 32 + q * 8;
        int n  = g * 128 + d;
        s16x8 f;
        #pragma unroll
        for (int j = 0; j < 8; j++) f[j] = (short)f2bf(B[(size_t)(kb + j) * FD + n]);
        return f;
    };
    auto load_afrag = [&](const u16* X, int kc) -> s16x8 {
        return *(const s16x8*)(X + (size_t)nl * XPAD + kc * 32 + q * 8);
    };

    auto run_phase = [&](const float* Wg, const float* Ug, const float* bias,
                         int nsteps, const int* slots, bool write_hm, bool write_out) {
        s16x8 wf[4][4], uf[4][4];
        #pragma unroll
        for (int kc = 0; kc < 4; kc++) {
            #pragma unroll
            for (int g = 0; g < 4; g++) {
                wf[kc][g] = load_bfrag_direct(Wg, kc, g);
                uf[kc][g] = load_bfrag_direct(Ug, kc, g);
            }
        }
        float bz[4];
        #pragma unroll
        for (int g = 0; g < 4; g++) bz[g] = bias[g * 128 + d];
        float cc[4] = {0.f, 0.f, 0.f, 0.f};

        #pragma unroll 1
        for (int t = 0; t < nsteps; t++) {
            int s = slots[t];
            f32x4 acc[4];
            #pragma unroll
            for (int g = 0; g < 4; g++) acc[g] = (f32x4){0.f, 0.f, 0.f, 0.f};
            #pragma unroll
            for (int kc = 0; kc < 4; kc++) {
                s16x8 a = (s < 0) ? *(const s16x8*)(&empty_s[kc * 32 + q * 8])
                                  : load_afrag(&xs[s][0][0], kc);
                #pragma unroll
                for (int g = 0; g < 4; g++)
                    acc[g] = __builtin_amdgcn_mfma_f32_16x16x32_bf16(a, wf[kc][g], acc[g], 0, 0, 0);
            }
            if (t > 0) {
                __syncthreads();
                const u16* hb = &hbuf[(t - 1) & 1][0][0];
                #pragma unroll
                for (int kc = 0; kc < 4; kc++) {
                    s16x8 a = load_afrag(hb, kc);
                    #pragma unroll
                    for (int g = 0; g < 4; g++)
                        acc[g] = __builtin_amdgcn_mfma_f32_16x16x32_bf16(a, uf[kc][g], acc[g], 0, 0, 0);
                }
            }
            bool last = (t == nsteps - 1);
            #pragma unroll
            for (int r2 = 0; r2 < 4; r2++) {
                int m = q * 4 + r2;
                float zi = acc[0][r2] + bz[0];
                float zf = acc[1][r2] + bz[1];
                float zg = acc[2][r2] + bz[2];
                float zo = acc[3][r2] + bz[3];
                float c  = sigm(zf) * cc[r2] + sigm(zi) * tanh_f(zg);
                cc[r2] = c;
                float h  = sigm(zo) * tanh_f(c);
                if (!last)          hbuf[t & 1][m][d] = f2bf(h);
                else if (write_hm)  xs[0][m][d] = f2bf(h);
                else if (write_out) emb[(row0 + m) * DIM + d] = h;
            }
        }
    };

    {
        const int slots_m[5] = {-1, 0, 1, 2, 3};
        run_phase(Wm, Um, bm, 5, slots_m, true, false);
    }
    {
        const int slots_s[3] = {4, 5, 0};
        run_phase(Ws, Us, bs, 3, slots_s, false, true);
    }
}

extern "C" void kernel_launch(void* const* d_in, const int* in_sizes, int n_in,
                              void* d_out, int out_size, void* d_ws, size_t ws_size,
                              hipStream_t stream) {
    const int*   names = (const int*)d_in[0];
    const int*   pids  = (const int*)d_in[1];
    const int*   sids  = (const int*)d_in[2];
    const float* table = (const float*)d_in[3];
    const float* Wm    = (const float*)d_in[4];
    const float* Um    = (const float*)d_in[5];
    const float* bm    = (const float*)d_in[6];
    const float* Ws    = (const float*)d_in[7];
    const float* Us    = (const float*)d_in[8];
    const float* bs    = (const float*)d_in[9];
    const float* bsv   = bs;
    const float* empt  = (const float*)d_in[10];
    float* emb  = (float*)d_out;
    u16* packed = (u16*)d_ws;

    l0_kernel<<<256, 256, 0, stream>>>(names, table, emb);

    const size_t packed_bytes = (size_t)4 * 4 * 32 * 64 * 8 * sizeof(u16);  // 512 KB
    const size_t t0_bytes     = 640 * sizeof(float);                        // c1 + uh1
    const bool ws_ok = ws_size >= packed_bytes + t0_bytes;

    if (ws_ok) {
        float* t0buf = (float*)((char*)d_ws + packed_bytes);
        repack_kernel<<<128, 256, 0, stream>>>(Wm, Um, Ws, Us, packed);
        init_t0_kernel<<<1, 128, 0, stream>>>(Wm, Um, bm, empt, t0buf);
        for (int l = 1; l < LAYERS; l++)
            layer5_kernel<<<NBLK, TPB, 0, stream>>>(emb, pids, sids, bm, bsv,
                                                    packed, t0buf, l);
    } else {
        for (int l = 1; l < LAYERS; l++)
            layer_kernel_direct<<<NBLK, TPB, 0, stream>>>(emb, pids, sids, Wm, Um, bm,
                                                          Ws, Us, bs, empt, l);
    }
}

// Round 7
// 1050.058 us; speedup vs baseline: 2.2594x; 1.0367x over previous
//
#include <hip/hip_runtime.h>

typedef unsigned short u16;
typedef short s16x8 __attribute__((ext_vector_type(8)));
typedef float f32x4 __attribute__((ext_vector_type(4)));

#define LAYERS   64
#define M_NODES  2048
#define DIM      128
#define FD       512
#define CHUNK    16
#define NBLK     128     // M_NODES / CHUNK
#define TPB      512     // 8 waves; wave wv owns hidden dims [wv*16, wv*16+16)
#define XPAD     136     // 128 + 8 pad u16 (16B-aligned rows)

__device__ __forceinline__ u16 f2bf(float f) {
    union { float f; unsigned int i; } v; v.f = f;
    unsigned int r = (v.i + 0x7FFFu + ((v.i >> 16) & 1u)) >> 16;
    return (u16)r;
}
__device__ __forceinline__ float bf2f(u16 h) {
    union { unsigned int i; float f; } v; v.i = ((unsigned int)h) << 16;
    return v.f;
}
__device__ __forceinline__ float sigm(float x) {
    return __builtin_amdgcn_rcpf(1.0f + __builtin_exp2f(-1.44269504f * x));
}
__device__ __forceinline__ float tanh_f(float x) {
    float ax = __builtin_fabsf(x);
    float t  = __builtin_exp2f(-2.88539008f * ax);   // exp(-2|x|)
    float r  = (1.0f - t) * __builtin_amdgcn_rcpf(1.0f + t);
    return __builtin_copysignf(r, x);
}

// ---------------- standalone layer 0 (fallback path only) ----------------
__global__ void l0_kernel(const int* __restrict__ names, const float* __restrict__ table,
                          float* __restrict__ emb) {
    int v = blockIdx.x * blockDim.x + threadIdx.x;      // 2048 rows * 32 float4
    if (v >= M_NODES * (DIM / 4)) return;
    int row = v >> 5, c = v & 31;
    const float4* src = (const float4*)(table + (size_t)names[row] * DIM);
    ((float4*)(emb + (size_t)row * DIM))[c] = src[c];
}

// =============== merged setup: repack (blocks 0-127) + t0 hoist (block 128) + l0 (129-384) ===============
// packed[(((mat*4+kc)*32+ntile)*64+lane)*8+j] = bf16(B[kc*32+(lane>>4)*8+j][ntile*16+(lane&15)])
// t0buf: [0..127] = c1; [128 + g*128 + d] = uh1[g][d]   (layer-invariant LSTM_m t=0)
// l0: emb[m] = table[names[m]] (fp32) and, if MIRROR, emb16[m] = bf16 of the same.
template <bool MIRROR>
__global__ void setup_kernel(const int* __restrict__ names, const float* __restrict__ table,
                             float* __restrict__ emb,
                             const float* __restrict__ Wm, const float* __restrict__ Um,
                             const float* __restrict__ Ws, const float* __restrict__ Us,
                             const float* __restrict__ bm, const float* __restrict__ empty,
                             u16* __restrict__ packed, float* __restrict__ t0buf,
                             u16* __restrict__ emb16) {
    const int blk = blockIdx.x;
    const int tid = threadIdx.x;
    if (blk < 128) {                                    // ---- repack ----
        int t = blk * 256 + tid;                        // 32768 threads
        int lane = t & 63, ntg = (t >> 6) & 31, kc = (t >> 11) & 3, mat = t >> 13;
        const float* B = (mat == 0) ? Wm : (mat == 1) ? Um : (mat == 2) ? Ws : Us;
        int q = lane >> 4, nl = lane & 15;
        int kb = kc * 32 + q * 8;
        int n  = ntg * 16 + nl;
        u16* dst = packed + ((((size_t)mat * 4 + kc) * 32 + ntg) * 64 + lane) * 8;
        #pragma unroll
        for (int j = 0; j < 8; j++) dst[j] = f2bf(B[(size_t)(kb + j) * FD + n]);
    } else if (blk == 128) {                            // ---- t0 hoist ----
        __shared__ float h1s[DIM];
        int dd = tid;
        if (dd < DIM) {
            float z0 = bm[dd], z1 = bm[256 + dd], z2 = bm[384 + dd];
            for (int k = 0; k < DIM; k++) {
                float e = empty[k];
                const float* Wr = Wm + (size_t)k * FD;
                z0 += e * Wr[dd];                       // i gate
                z1 += e * Wr[256 + dd];                 // g gate
                z2 += e * Wr[384 + dd];                 // o gate (f irrelevant: c_prev=0)
            }
            float c1 = sigm(z0) * tanh_f(z1);
            float h1 = sigm(z2) * tanh_f(c1);
            t0buf[dd] = c1;
            h1s[dd] = h1;
        }
        __syncthreads();
        if (dd < DIM) {
            float u0 = 0.f, u1 = 0.f, u2 = 0.f, u3 = 0.f;
            for (int k = 0; k < DIM; k++) {
                float hb = bf2f(f2bf(h1s[k]));          // same bf16 rounding as the MFMA path
                const float* Ur = Um + (size_t)k * FD;
                u0 += hb * bf2f(f2bf(Ur[dd]));
                u1 += hb * bf2f(f2bf(Ur[128 + dd]));
                u2 += hb * bf2f(f2bf(Ur[256 + dd]));
                u3 += hb * bf2f(f2bf(Ur[384 + dd]));
            }
            t0buf[128 + 0 * 128 + dd] = u0;
            t0buf[128 + 1 * 128 + dd] = u1;
            t0buf[128 + 2 * 128 + dd] = u2;
            t0buf[128 + 3 * 128 + dd] = u3;
        }
    } else {                                            // ---- l0 ----
        int v = (blk - 129) * 256 + tid;                // 65536 float4s
        if (v >= M_NODES * (DIM / 4)) return;
        int row = v >> 5, c = v & 31;
        const float4* src = (const float4*)(table + (size_t)names[row] * DIM);
        float4 vv = src[c];
        ((float4*)(emb + (size_t)row * DIM))[c] = vv;
        if (MIRROR) {
            ushort4 w;
            w.x = f2bf(vv.x); w.y = f2bf(vv.y); w.z = f2bf(vv.z); w.w = f2bf(vv.w);
            *(ushort4*)(emb16 + (size_t)row * DIM + c * 4) = w;
        }
    }
}

// ======================= per-layer kernel, merged 5-step schedule =======================
// Coherence via dispatch boundaries (proven cheapest across r1-r5). MIRROR: gather reads the
// bf16 emb16 mirror (half bytes, zero conversion, straight 16B LDS copies); step5 writes both
// fp32 emb and emb16. Steps (dependency-minimal 5 barriers):
//   S0 gather | step1 (reg-only): m-t1 = zxm0+uh1 || s-t0 = zxs0 | S1 | step2: m-t2 | S2 |
//   step3: m-t3 || s-t1 (2x MFMA ILP) | S3 | step4: m-t4 -> h_m | S4 | step5: s-t2 -> emb.
template <bool MIRROR>
__global__ __launch_bounds__(TPB, 1) void layer5_kernel(
    float* __restrict__ emb, const int* __restrict__ prop_ids, const int* __restrict__ super_ids,
    const float* __restrict__ bm, const float* __restrict__ bs,
    const u16* __restrict__ packed, const float* __restrict__ t0buf,
    u16* __restrict__ emb16, int l) {

    // slots 0..3: prop embeddings (slot 0 reused for h_m); slots 4..5: super embeddings
    __shared__ __align__(16) u16 xs[6][CHUNK][XPAD];
    __shared__ __align__(16) u16 hbM[2][CHUNK][XPAD];
    __shared__ __align__(16) u16 hbS[2][CHUNK][XPAD];

    const int tid  = threadIdx.x;
    const int b    = blockIdx.x;
    const int g0   = b * CHUNK;
    const int wv   = tid >> 6;          // 0..7
    const int lane = tid & 63;
    const int q    = lane >> 4, nl = lane & 15;
    const int d    = wv * 16 + nl;      // this lane's hidden dim

    auto ldB = [&](int mat, int kc, int g) -> s16x8 {
        return *(const s16x8*)(packed + ((((size_t)mat * 4 + kc) * 32 + (g * 8 + wv)) * 64 + lane) * 8);
    };
    auto load_afrag = [&](const u16* X /* [CHUNK][XPAD] base */, int kc) -> s16x8 {
        return *(const s16x8*)(X + (size_t)nl * XPAD + kc * 32 + q * 8);
    };

    // ---- gather: 96 rows -> bf16 LDS tiles (waves 0-5) ----
    if (tid < 384) {
        int quarter = tid & 3;
        int r    = tid >> 2;
        int slot = r >> 4;
        int node = r & 15;
        size_t idx;
        if (slot < 4) idx = (size_t)prop_ids [((size_t)l * M_NODES + g0 + node) * 4 + slot];
        else          idx = (size_t)super_ids[((size_t)l * M_NODES + g0 + node) * 2 + (slot - 4)];
        if (MIRROR) {
            // bf16 row: 64B per lane, straight copy (no conversion)
            const s16x8* src = (const s16x8*)(emb16 + idx * DIM) + quarter * 4;
            u16* dst = &xs[slot][node][quarter * 32];
            #pragma unroll
            for (int j = 0; j < 4; j++) *(s16x8*)(dst + j * 8) = src[j];
        } else {
            const f32x4* src = (const f32x4*)(emb + idx * DIM) + quarter * 8;
            u16* dst = &xs[slot][node][0];
            int e0 = quarter * 32;
            #pragma unroll
            for (int j = 0; j < 8; j++) {
                f32x4 v = src[j];
                ushort4 w;
                w.x = f2bf(v[0]); w.y = f2bf(v[1]); w.z = f2bf(v[2]); w.w = f2bf(v[3]);
                *(ushort4*)(dst + e0 + j * 4) = w;
            }
        }
    }

    // ---- per-thread constants (all waves, overlaps gather) ----
    float bzm[4], bzs[4], uh1[4];
    #pragma unroll
    for (int g = 0; g < 4; g++) {
        bzm[g] = bm[g * 128 + d];
        bzs[g] = bs[g * 128 + d];
        uh1[g] = t0buf[128 + g * 128 + d];
    }
    const float c1 = t0buf[d];

    // Ws fragments for the Zx phase (dies after zxs; reloaded at step5)
    s16x8 wfs[4][4];
    #pragma unroll
    for (int kc = 0; kc < 4; kc++)
        #pragma unroll
        for (int g = 0; g < 4; g++) wfs[kc][g] = ldB(2, kc, g);

    __syncthreads();                                   // S0: gather visible

    // gates + store; mode 0: hbM[parity], 3: hbS[parity], 1: xs[0] (h_m), 2: emb (+mirror)
    auto gates = [&](const f32x4* acc, const float* bz, float* cc, int mode, int parity) {
        #pragma unroll
        for (int r2 = 0; r2 < 4; r2++) {
            int m = q * 4 + r2;
            float zi = acc[0][r2] + bz[0];
            float zf = acc[1][r2] + bz[1];
            float zg = acc[2][r2] + bz[2];
            float zo = acc[3][r2] + bz[3];
            float c  = sigm(zf) * cc[r2] + sigm(zi) * tanh_f(zg);
            cc[r2] = c;
            float h  = sigm(zo) * tanh_f(c);
            if (mode == 0)      hbM[parity][m][d] = f2bf(h);
            else if (mode == 3) hbS[parity][m][d] = f2bf(h);
            else if (mode == 1) xs[0][m][d] = f2bf(h);
            else {
                emb[((size_t)l * M_NODES + g0 + m) * DIM + d] = h;
                if (MIRROR) emb16[((size_t)l * M_NODES + g0 + m) * DIM + d] = f2bf(h);
            }
        }
    };

    // ---- Zx: zxs0, zxs1 = sup@Ws ----
    f32x4 zxs0[4], zxs1[4];
    #pragma unroll
    for (int g = 0; g < 4; g++) { zxs0[g] = (f32x4){0.f,0.f,0.f,0.f}; zxs1[g] = (f32x4){0.f,0.f,0.f,0.f}; }
    #pragma unroll
    for (int kc = 0; kc < 4; kc++) {
        s16x8 a4 = load_afrag(&xs[4][0][0], kc);
        s16x8 a5 = load_afrag(&xs[5][0][0], kc);
        #pragma unroll
        for (int g = 0; g < 4; g++) {
            zxs0[g] = __builtin_amdgcn_mfma_f32_16x16x32_bf16(a4, wfs[kc][g], zxs0[g], 0, 0, 0);
            zxs1[g] = __builtin_amdgcn_mfma_f32_16x16x32_bf16(a5, wfs[kc][g], zxs1[g], 0, 0, 0);
        }
    }
    // ---- Zx: zxm[0..3] = prop@Wm (wfm scoped to die after) ----
    f32x4 zxm[4][4];
    {
        s16x8 wfm[4][4];
        #pragma unroll
        for (int kc = 0; kc < 4; kc++)
            #pragma unroll
            for (int g = 0; g < 4; g++) wfm[kc][g] = ldB(0, kc, g);
        #pragma unroll
        for (int s = 0; s < 4; s++) {
            #pragma unroll
            for (int g = 0; g < 4; g++) zxm[s][g] = (f32x4){0.f, 0.f, 0.f, 0.f};
            #pragma unroll
            for (int kc = 0; kc < 4; kc++) {
                s16x8 a = load_afrag(&xs[s][0][0], kc);
                #pragma unroll
                for (int g = 0; g < 4; g++)
                    zxm[s][g] = __builtin_amdgcn_mfma_f32_16x16x32_bf16(a, wfm[kc][g], zxm[s][g], 0, 0, 0);
            }
        }
    }

    s16x8 ufm[4][4];
    #pragma unroll
    for (int kc = 0; kc < 4; kc++)
        #pragma unroll
        for (int g = 0; g < 4; g++) ufm[kc][g] = ldB(1, kc, g);

    float ccm[4] = {c1, c1, c1, c1};
    float ccs[4] = {0.f, 0.f, 0.f, 0.f};

    {   // step1 (register-only): m-t1 = zxm[0]+uh1  ||  s-t0 = zxs0
        f32x4 accM[4];
        #pragma unroll
        for (int g = 0; g < 4; g++) accM[g] = zxm[0][g] + uh1[g];
        gates(accM, bzm, ccm, 0, 1);                   // write hbM[1]
        gates(zxs0, bzs, ccs, 3, 0);                   // write hbS[0]
    }
    __syncthreads();                                   // S1

    {   // step2: m-t2 = zxm[1] + hbM[1]@Um
        f32x4 acc[4];
        #pragma unroll
        for (int g = 0; g < 4; g++) acc[g] = zxm[1][g];
        #pragma unroll
        for (int kc = 0; kc < 4; kc++) {
            s16x8 a = load_afrag(&hbM[1][0][0], kc);
            #pragma unroll
            for (int g = 0; g < 4; g++)
                acc[g] = __builtin_amdgcn_mfma_f32_16x16x32_bf16(a, ufm[kc][g], acc[g], 0, 0, 0);
        }
        gates(acc, bzm, ccm, 0, 0);                    // write hbM[0]
    }
    __syncthreads();                                   // S2

    s16x8 ufs[4][4];
    #pragma unroll
    for (int kc = 0; kc < 4; kc++)
        #pragma unroll
        for (int g = 0; g < 4; g++) ufs[kc][g] = ldB(3, kc, g);

    {   // step3: m-t3 (zxm[2] + hbM[0]@Um)  ||  s-t1 (zxs1 + hbS[0]@Us) — 2x MFMA ILP
        f32x4 am[4], as_[4];
        #pragma unroll
        for (int g = 0; g < 4; g++) { am[g] = zxm[2][g]; as_[g] = zxs1[g]; }
        #pragma unroll
        for (int kc = 0; kc < 4; kc++) {
            s16x8 aM = load_afrag(&hbM[0][0][0], kc);
            s16x8 aS = load_afrag(&hbS[0][0][0], kc);
            #pragma unroll
            for (int g = 0; g < 4; g++) {
                am[g]  = __builtin_amdgcn_mfma_f32_16x16x32_bf16(aM, ufm[kc][g], am[g],  0, 0, 0);
                as_[g] = __builtin_amdgcn_mfma_f32_16x16x32_bf16(aS, ufs[kc][g], as_[g], 0, 0, 0);
            }
        }
        gates(am,  bzm, ccm, 0, 1);                    // write hbM[1]
        gates(as_, bzs, ccs, 3, 1);                    // write hbS[1]
    }
    __syncthreads();                                   // S3

    {   // step4: m-t4 = zxm[3] + hbM[1]@Um -> h_m -> xs[0]
        f32x4 acc[4];
        #pragma unroll
        for (int g = 0; g < 4; g++) acc[g] = zxm[3][g];
        #pragma unroll
        for (int kc = 0; kc < 4; kc++) {
            s16x8 a = load_afrag(&hbM[1][0][0], kc);
            #pragma unroll
            for (int g = 0; g < 4; g++)
                acc[g] = __builtin_amdgcn_mfma_f32_16x16x32_bf16(a, ufm[kc][g], acc[g], 0, 0, 0);
        }
        gates(acc, bzm, ccm, 1, 0);                    // h_m -> xs[0]
    }
    __syncthreads();                                   // S4

    {   // step5: s-t2 = h_m@Ws + hbS[1]@Us -> fp32 layer output (+ bf16 mirror)
        s16x8 wfs2[4][4];
        #pragma unroll
        for (int kc = 0; kc < 4; kc++)
            #pragma unroll
            for (int g = 0; g < 4; g++) wfs2[kc][g] = ldB(2, kc, g);
        f32x4 acc[4];
        #pragma unroll
        for (int g = 0; g < 4; g++) acc[g] = (f32x4){0.f, 0.f, 0.f, 0.f};
        #pragma unroll
        for (int kc = 0; kc < 4; kc++) {
            s16x8 a0 = load_afrag(&xs[0][0][0], kc);
            s16x8 aS = load_afrag(&hbS[1][0][0], kc);
            #pragma unroll
            for (int g = 0; g < 4; g++) {
                acc[g] = __builtin_amdgcn_mfma_f32_16x16x32_bf16(a0, wfs2[kc][g], acc[g], 0, 0, 0);
                acc[g] = __builtin_amdgcn_mfma_f32_16x16x32_bf16(aS, ufs[kc][g],  acc[g], 0, 0, 0);
            }
        }
        gates(acc, bzs, ccs, 2, 0);                    // emb out
    }
}

// ----------------------------- fallback (no workspace): proven per-layer kernel -----------------------------
__global__ __launch_bounds__(TPB, 1) void layer_kernel_direct(
    float* __restrict__ emb, const int* __restrict__ prop_ids, const int* __restrict__ super_ids,
    const float* __restrict__ Wm, const float* __restrict__ Um, const float* __restrict__ bm,
    const float* __restrict__ Ws, const float* __restrict__ Us, const float* __restrict__ bs,
    const float* __restrict__ empty, int l) {

    __shared__ __align__(16) u16  xs[6][CHUNK][XPAD];
    __shared__ __align__(16) u16  hbuf[2][CHUNK][XPAD];
    __shared__ __align__(16) u16  empty_s[XPAD];

    const int tid  = threadIdx.x;
    const int b    = blockIdx.x;
    const int g0   = b * CHUNK;
    const size_t row0 = (size_t)l * M_NODES + g0;

    const int wv   = tid >> 6;
    const int lane = tid & 63;
    const int q    = lane >> 4, nl = lane & 15;
    const int d    = wv * 16 + nl;

    if (tid < 384) {
        int quarter = tid & 3;
        int r    = tid >> 2;
        int slot = r >> 4;
        int node = r & 15;
        size_t idx;
        if (slot < 4) idx = (size_t)prop_ids [((size_t)l * M_NODES + g0 + node) * 4 + slot];
        else          idx = (size_t)super_ids[((size_t)l * M_NODES + g0 + node) * 2 + (slot - 4)];
        const float4* src = (const float4*)(emb + idx * DIM);
        u16* dst = &xs[slot][node][0];
        int e0 = quarter * 32;
        #pragma unroll
        for (int j = 0; j < 8; j++) {
            float4 v = src[(e0 >> 2) + j];
            int o = e0 + j * 4;
            dst[o] = f2bf(v.x); dst[o + 1] = f2bf(v.y);
            dst[o + 2] = f2bf(v.z); dst[o + 3] = f2bf(v.w);
        }
    } else if (tid < 384 + 128) {
        int dd = tid - 384;
        empty_s[dd] = f2bf(empty[dd]);
    }
    __syncthreads();

    auto load_bfrag_direct = [&](const float* B, int kc, int g) -> s16x8 {
        int kb = kc * 32 + q * 8;
        int n  = g * 128 + d;
        s16x8 f;
        #pragma unroll
        for (int j = 0; j < 8; j++) f[j] = (short)f2bf(B[(size_t)(kb + j) * FD + n]);
        return f;
    };
    auto load_afrag = [&](const u16* X, int kc) -> s16x8 {
        return *(const s16x8*)(X + (size_t)nl * XPAD + kc * 32 + q * 8);
    };

    auto run_phase = [&](const float* Wg, const float* Ug, const float* bias,
                         int nsteps, const int* slots, bool write_hm, bool write_out) {
        s16x8 wf[4][4], uf[4][4];
        #pragma unroll
        for (int kc = 0; kc < 4; kc++) {
            #pragma unroll
            for (int g = 0; g < 4; g++) {
                wf[kc][g] = load_bfrag_direct(Wg, kc, g);
                uf[kc][g] = load_bfrag_direct(Ug, kc, g);
            }
        }
        float bz[4];
        #pragma unroll
        for (int g = 0; g < 4; g++) bz[g] = bias[g * 128 + d];
        float cc[4] = {0.f, 0.f, 0.f, 0.f};

        #pragma unroll 1
        for (int t = 0; t < nsteps; t++) {
            int s = slots[t];
            f32x4 acc[4];
            #pragma unroll
            for (int g = 0; g < 4; g++) acc[g] = (f32x4){0.f, 0.f, 0.f, 0.f};
            #pragma unroll
            for (int kc = 0; kc < 4; kc++) {
                s16x8 a = (s < 0) ? *(const s16x8*)(&empty_s[kc * 32 + q * 8])
                                  : load_afrag(&xs[s][0][0], kc);
                #pragma unroll
                for (int g = 0; g < 4; g++)
                    acc[g] = __builtin_amdgcn_mfma_f32_16x16x32_bf16(a, wf[kc][g], acc[g], 0, 0, 0);
            }
            if (t > 0) {
                __syncthreads();
                const u16* hb = &hbuf[(t - 1) & 1][0][0];
                #pragma unroll
                for (int kc = 0; kc < 4; kc++) {
                    s16x8 a = load_afrag(hb, kc);
                    #pragma unroll
                    for (int g = 0; g < 4; g++)
                        acc[g] = __builtin_amdgcn_mfma_f32_16x16x32_bf16(a, uf[kc][g], acc[g], 0, 0, 0);
                }
            }
            bool last = (t == nsteps - 1);
            #pragma unroll
            for (int r2 = 0; r2 < 4; r2++) {
                int m = q * 4 + r2;
                float zi = acc[0][r2] + bz[0];
                float zf = acc[1][r2] + bz[1];
                float zg = acc[2][r2] + bz[2];
                float zo = acc[3][r2] + bz[3];
                float c  = sigm(zf) * cc[r2] + sigm(zi) * tanh_f(zg);
                cc[r2] = c;
                float h  = sigm(zo) * tanh_f(c);
                if (!last)          hbuf[t & 1][m][d] = f2bf(h);
                else if (write_hm)  xs[0][m][d] = f2bf(h);
                else if (write_out) emb[(row0 + m) * DIM + d] = h;
            }
        }
    };

    {
        const int slots_m[5] = {-1, 0, 1, 2, 3};
        run_phase(Wm, Um, bm, 5, slots_m, true, false);
    }
    {
        const int slots_s[3] = {4, 5, 0};
        run_phase(Ws, Us, bs, 3, slots_s, false, true);
    }
}

extern "C" void kernel_launch(void* const* d_in, const int* in_sizes, int n_in,
                              void* d_out, int out_size, void* d_ws, size_t ws_size,
                              hipStream_t stream) {
    const int*   names = (const int*)d_in[0];
    const int*   pids  = (const int*)d_in[1];
    const int*   sids  = (const int*)d_in[2];
    const float* table = (const float*)d_in[3];
    const float* Wm    = (const float*)d_in[4];
    const float* Um    = (const float*)d_in[5];
    const float* bm    = (const float*)d_in[6];
    const float* Ws    = (const float*)d_in[7];
    const float* Us    = (const float*)d_in[8];
    const float* bs    = (const float*)d_in[9];
    const float* empt  = (const float*)d_in[10];
    float* emb  = (float*)d_out;
    u16* packed = (u16*)d_ws;

    const size_t packed_bytes = (size_t)4 * 4 * 32 * 64 * 8 * sizeof(u16);  // 512 KB
    const size_t t0_bytes     = 640 * sizeof(float);
    const size_t mirror_off   = (size_t)1 << 20;                            // 1 MB
    const size_t mirror_bytes = (size_t)LAYERS * M_NODES * DIM * sizeof(u16); // 32 MB
    const bool ws_packed = ws_size >= packed_bytes + t0_bytes;
    const bool ws_mirror = ws_size >= mirror_off + mirror_bytes;

    if (ws_packed) {
        float* t0buf = (float*)((char*)d_ws + packed_bytes);
        u16*   emb16 = ws_mirror ? (u16*)((char*)d_ws + mirror_off) : (u16*)nullptr;
        if (ws_mirror) {
            setup_kernel<true><<<385, 256, 0, stream>>>(names, table, emb, Wm, Um, Ws, Us,
                                                        bm, empt, packed, t0buf, emb16);
            for (int l = 1; l < LAYERS; l++)
                layer5_kernel<true><<<NBLK, TPB, 0, stream>>>(emb, pids, sids, bm, bs,
                                                              packed, t0buf, emb16, l);
        } else {
            setup_kernel<false><<<385, 256, 0, stream>>>(names, table, emb, Wm, Um, Ws, Us,
                                                         bm, empt, packed, t0buf, emb16);
            for (int l = 1; l < LAYERS; l++)
                layer5_kernel<false><<<NBLK, TPB, 0, stream>>>(emb, pids, sids, bm, bs,
                                                               packed, t0buf, emb16, l);
        }
    } else {
        l0_kernel<<<256, 256, 0, stream>>>(names, table, emb);
        for (int l = 1; l < LAYERS; l++)
            layer_kernel_direct<<<NBLK, TPB, 0, stream>>>(emb, pids, sids, Wm, Um, bm,
                                                          Ws, Us, bs, empt, l);
    }
}